// Round 3
// baseline (1285.108 us; speedup 1.0000x reference)
//
#include <hip/hip_runtime.h>
#include <cstdint>
#include <cstddef>

// RobustGCN forward on MI355X.
// Pipeline:
//   1. graph prep: degree count (atomics) -> dd=(deg^-0.5, deg^-1); padded scan ->
//      bucketed two-pass partition -> CSR (bucket = src>>6, CSR node-ordered so
//      bucket regions are contiguous; partB appends (src,dst) pairs per bucket,
//      partC scatters within-bucket via LDS cursors -> full-line writebacks only)
//   2. GEMM1 (f16 MFMA): Hcat = [elu(x@Wm0+bm0) | relu(x@Wv0+bv0)]  (N x 512)
//   3. GEMM2 (f16 MFMA, block-diag W) with FUSED attention epilogue:
//        m = elu(.@Wm1+bm1); v = relu(.@Wv1+bv1)+1e-6; a=exp(-v)
//        Mcat[r][c] = pack_h2(m*a, v*a*a)        (one uint per (node,class))
//   4. fused dual SpMM (CSR, wave/node, lane/class, 4-edge int4 batches)
//      + sample*sqrt(var) + log_softmax

typedef _Float16 h8 __attribute__((ext_vector_type(8)));
typedef _Float16 h2 __attribute__((ext_vector_type(2)));
typedef float f32x4 __attribute__((ext_vector_type(4)));
typedef unsigned int uint32;

static __device__ __forceinline__ float elu_f(float z) {
  return z > 0.f ? z : expm1f(z);
}

// ---------------- graph prep ----------------
__global__ void deg_count_k(const int* __restrict__ esrc, int E, int* __restrict__ cnt) {
  int e = blockIdx.x * 256 + threadIdx.x;
  if (e < E) atomicAdd(&cnt[esrc[e]], 1);
}

__global__ void deg_fin_k(const int* __restrict__ cnt, float2* __restrict__ dd, int n) {
  int v = blockIdx.x * 256 + threadIdx.x;
  if (v < n) {
    float d = (float)(cnt[v] + 1);  // +1 self loop
    dd[v] = make_float2(rsqrtf(d), 1.f / d);
  }
}

// exclusive scan of PADDED counts ((cnt+3)&~3) so every CSR row start is 16B-aligned
__global__ void scan1_k(const int* __restrict__ cnt, int* __restrict__ excl,
                        int* __restrict__ bsum, int n) {
  __shared__ int sh[256];
  int t = threadIdx.x, idx = blockIdx.x * 256 + t;
  int v = (idx < n) ? ((cnt[idx] + 3) & ~3) : 0;
  sh[t] = v;
  __syncthreads();
  for (int off = 1; off < 256; off <<= 1) {
    int add = (t >= off) ? sh[t - off] : 0;
    __syncthreads();
    sh[t] += add;
    __syncthreads();
  }
  if (idx < n) excl[idx] = sh[t] - v;
  if (t == 255) bsum[blockIdx.x] = sh[255];
}

__global__ void scan2_k(const int* __restrict__ bsum, int* __restrict__ boff, int nb) {
  __shared__ int sh[512];
  int t = threadIdx.x;
  int v = (t < nb) ? bsum[t] : 0;
  sh[t] = v;
  __syncthreads();
  for (int off = 1; off < 512; off <<= 1) {
    int add = (t >= off) ? sh[t - off] : 0;
    __syncthreads();
    sh[t] += add;
    __syncthreads();
  }
  if (t < nb) boff[t] = sh[t] - v;
}

__global__ void scan3_k(int* __restrict__ excl, const int* __restrict__ boff, int n) {
  int idx = blockIdx.x * 256 + threadIdx.x;
  if (idx < n) excl[idx] += boff[blockIdx.x];
}

// bucket cursors: bucket b covers nodes [64b, 64b+64); CSR region starts at rs[64b]
__global__ void bcur_init_k(const int* __restrict__ rs, int* __restrict__ bcur, int nbuck) {
  int b = blockIdx.x * 256 + threadIdx.x;
  if (b < nbuck) bcur[b] = rs[b * 64];
}

// pass B: append (src,dst) pairs into bucket-contiguous regions (sequential frontiers)
__global__ void partB_k(const int* __restrict__ esrc, const int* __restrict__ edst,
                        int* __restrict__ bcur, int2* __restrict__ pairs, int E) {
  int e = blockIdx.x * 256 + threadIdx.x;
  if (e < E) {
    int s = esrc[e];
    int pos = atomicAdd(&bcur[s >> 6], 1);
    pairs[pos] = make_int2(s, edst[e]);
  }
}

// pass C: block per bucket; LDS per-node cursors; scatter dst into the bucket's
// ~8KB CSR region (L2-resident -> full-line writeback).
__global__ __launch_bounds__(256) void partC_k(
    const int2* __restrict__ pairs, const int* __restrict__ rs,
    const int* __restrict__ cnt, int* __restrict__ csr, int n) {
  __shared__ int lcur[64];
  __shared__ int lsum;
  const int b = blockIdx.x;
  const int nb0 = b * 64;
  const int t = threadIdx.x;
  int c = 0;
  if (t < 64) {
    int node = nb0 + t;
    c = (node < n) ? cnt[node] : 0;
    lcur[t] = (node < n) ? rs[node] : 0;
    int s = c;
#pragma unroll
    for (int off = 32; off; off >>= 1) s += __shfl_xor(s, off, 64);
    if (t == 0) lsum = s;
  }
  __syncthreads();
  const int nE = lsum;
  const int base = rs[nb0];
  for (int i = t; i < nE; i += 256) {
    int2 pr = pairs[base + i];
    int pos = atomicAdd(&lcur[pr.x & 63], 1);
    csr[pos] = pr.y;
  }
}

// ---------------- weight prep: transpose + f16 + fuse ----------------
__global__ void prep_w_k(const float* __restrict__ Wm0, const float* __restrict__ Wv0,
                         const float* __restrict__ Wm1, const float* __restrict__ Wv1,
                         _Float16* __restrict__ W1t, _Float16* __restrict__ W2t) {
  int idx = blockIdx.x * 256 + threadIdx.x;
  if (idx < 512 * 512) {
    int n = idx >> 9, k = idx & 511;
    float v = (n < 256) ? Wm0[k * 256 + n] : Wv0[k * 256 + (n - 256)];
    W1t[idx] = (_Float16)v;
  }
  if (idx < 128 * 512) {
    int n = idx >> 9, k = idx & 511;
    float v = 0.f;
    if (n < 64) { if (k < 256) v = Wm1[k * 64 + n]; }
    else        { if (k >= 256) v = Wv1[(k - 256) * 64 + (n - 64)]; }
    W2t[idx] = (_Float16)v;
  }
}

// ---------------- GEMM1: Hcat = act(x @ W1t^T + b) ----------------
// BM=BN=128, BK=32, 256 threads (4 waves 2x2), wave = 4x4 of 16x16x32 MFMA.
__global__ __launch_bounds__(256) void gemm1_k(
    const float* __restrict__ A, const _Float16* __restrict__ Bt,
    const float* __restrict__ b0, const float* __restrict__ b1,
    _Float16* __restrict__ out, int M, int K) {
  __shared__ _Float16 As[128 * 40];
  __shared__ _Float16 Bs[128 * 40];
  const int bid = blockIdx.x;
  const int mt = bid >> 2, nt = bid & 3;  // nt inner -> A-tile L2/L3 reuse
  const int m0 = mt * 128, n0 = nt * 128;
  const int t = threadIdx.x;
  const int lane = t & 63;
  const int wave = t >> 6;
  const int wm = wave >> 1, wn = wave & 1;
  const int lr = lane & 15, quad = lane >> 4;

  f32x4 acc[4][4] = {};

  for (int kt = 0; kt < K; kt += 32) {
#pragma unroll
    for (int i = 0; i < 2; i++) {
      int c = t + i * 256;
      int row = c >> 2, kc = (c & 3) * 8;
      int gr = m0 + row;
      if (gr > M - 1) gr = M - 1;
      const float* srcf = A + (size_t)gr * K + kt + kc;
      float4 f0 = ((const float4*)srcf)[0];
      float4 f1 = ((const float4*)srcf)[1];
      *(h8*)&As[row * 40 + kc] =
          h8{(_Float16)f0.x, (_Float16)f0.y, (_Float16)f0.z, (_Float16)f0.w,
             (_Float16)f1.x, (_Float16)f1.y, (_Float16)f1.z, (_Float16)f1.w};
      *(h8*)&Bs[row * 40 + kc] =
          *(const h8*)(Bt + (size_t)(n0 + row) * K + kt + kc);
    }
    __syncthreads();
    h8 af[4], bf[4];
#pragma unroll
    for (int i = 0; i < 4; i++)
      af[i] = *(h8*)&As[(wm * 64 + i * 16 + lr) * 40 + quad * 8];
#pragma unroll
    for (int j = 0; j < 4; j++)
      bf[j] = *(h8*)&Bs[(wn * 64 + j * 16 + lr) * 40 + quad * 8];
#pragma unroll
    for (int i = 0; i < 4; i++)
#pragma unroll
      for (int j = 0; j < 4; j++)
        acc[i][j] = __builtin_amdgcn_mfma_f32_16x16x32_f16(af[i], bf[j], acc[i][j], 0, 0, 0);
    __syncthreads();
  }

#pragma unroll
  for (int j = 0; j < 4; j++) {
    int gc = n0 + wn * 64 + j * 16 + lr;
    float bj = (gc < 256) ? b0[gc] : b1[gc - 256];
#pragma unroll
    for (int i = 0; i < 4; i++) {
#pragma unroll
      for (int r = 0; r < 4; r++) {
        int gr = m0 + wm * 64 + i * 16 + quad * 4 + r;
        if (gr < M) {
          float z = acc[i][j][r] + bj;
          float v = (gc < 256) ? elu_f(z) : fmaxf(z, 0.f);
          out[(size_t)gr * 512 + gc] = (_Float16)v;
        }
      }
    }
  }
}

// ---------------- GEMM2 + fused attention ----------------
// BM=128, N=128 (cols 0..63 mean, 64..127 var). 4 waves, each wave owns 32 rows
// (2 i-tiles) x all 8 j-tiles -> a lane holds mean col c (j<4) AND var col c
// (j+4) in registers -> attn computed in-register, packed h2 store to Mcat.
__global__ __launch_bounds__(256) void gemm2_k(
    const _Float16* __restrict__ A, const _Float16* __restrict__ Bt,
    const float* __restrict__ bm1, const float* __restrict__ bv1,
    uint32* __restrict__ Mcat, int M, int K) {
  __shared__ _Float16 As[128 * 40];
  __shared__ _Float16 Bs[128 * 40];
  const int m0 = blockIdx.x * 128;
  const int t = threadIdx.x;
  const int lane = t & 63;
  const int wave = t >> 6;
  const int lr = lane & 15, quad = lane >> 4;

  f32x4 acc[2][8] = {};

  for (int kt = 0; kt < K; kt += 32) {
#pragma unroll
    for (int i = 0; i < 2; i++) {
      int c = t + i * 256;
      int row = c >> 2, kc = (c & 3) * 8;
      int gr = m0 + row;
      if (gr > M - 1) gr = M - 1;
      *(h8*)&As[row * 40 + kc] = *(const h8*)(A + (size_t)gr * K + kt + kc);
      *(h8*)&Bs[row * 40 + kc] = *(const h8*)(Bt + (size_t)row * K + kt + kc);
    }
    __syncthreads();
    h8 af[2], bf[8];
#pragma unroll
    for (int i = 0; i < 2; i++)
      af[i] = *(h8*)&As[(wave * 32 + i * 16 + lr) * 40 + quad * 8];
#pragma unroll
    for (int j = 0; j < 8; j++)
      bf[j] = *(h8*)&Bs[(j * 16 + lr) * 40 + quad * 8];
#pragma unroll
    for (int i = 0; i < 2; i++)
#pragma unroll
      for (int j = 0; j < 8; j++)
        acc[i][j] = __builtin_amdgcn_mfma_f32_16x16x32_f16(af[i], bf[j], acc[i][j], 0, 0, 0);
    __syncthreads();
  }

#pragma unroll
  for (int jm = 0; jm < 4; jm++) {
    int c = jm * 16 + lr;                 // class col 0..63
    float bm = bm1[c], bv = bv1[c];
#pragma unroll
    for (int i = 0; i < 2; i++) {
#pragma unroll
      for (int r = 0; r < 4; r++) {
        int gr = m0 + wave * 32 + i * 16 + quad * 4 + r;
        if (gr < M) {
          float zm = acc[i][jm][r] + bm;
          float zv = acc[i][4 + jm][r] + bv;
          float m = elu_f(zm);
          float v = fmaxf(zv, 0.f) + 1e-6f;
          float a = __expf(-v);
          h2 pk;
          pk.x = (_Float16)(m * a);       // mean*attn
          pk.y = (_Float16)(v * a * a);   // var*attn^2
          Mcat[(size_t)gr * 64 + c] = __builtin_bit_cast(uint32, pk);
        }
      }
    }
  }
}

// ---------------- fused dual SpMM + reparam + log_softmax ----------------
// wave per node row, lane = class (CLS=64). 4-edge batches: one int4 csr load
// (16B-aligned via padded row starts) -> 4 independent dd + Mcat gathers.
__global__ __launch_bounds__(256) void spmm_final_k(
    const uint32* __restrict__ Mcat, const float2* __restrict__ dd,
    const int* __restrict__ row_start, const int* __restrict__ cnt,
    const int* __restrict__ csr, const float* __restrict__ sample,
    float* __restrict__ out, int n) {
  int wid = threadIdx.x >> 6, lane = threadIdx.x & 63;
  int r = blockIdx.x * 4 + wid;
  if (r >= n) return;
  float2 wr = dd[r];
  h2 self = __builtin_bit_cast(h2, Mcat[(size_t)r * 64 + lane]);
  float Sm = wr.x * (float)self.x;
  float Sv = wr.y * (float)self.y;
  int start = __builtin_amdgcn_readfirstlane(row_start[r]);
  int c = __builtin_amdgcn_readfirstlane(cnt[r]);
  int j = 0;
  for (; j + 4 <= c; j += 4) {
    int4 d4 = *(const int4*)(csr + start + j);
    float2 w0 = dd[d4.x];
    float2 w1 = dd[d4.y];
    float2 w2 = dd[d4.z];
    float2 w3 = dd[d4.w];
    h2 p0 = __builtin_bit_cast(h2, Mcat[(size_t)d4.x * 64 + lane]);
    h2 p1 = __builtin_bit_cast(h2, Mcat[(size_t)d4.y * 64 + lane]);
    h2 p2 = __builtin_bit_cast(h2, Mcat[(size_t)d4.z * 64 + lane]);
    h2 p3 = __builtin_bit_cast(h2, Mcat[(size_t)d4.w * 64 + lane]);
    Sm += w0.x * (float)p0.x; Sv += w0.y * (float)p0.y;
    Sm += w1.x * (float)p1.x; Sv += w1.y * (float)p1.y;
    Sm += w2.x * (float)p2.x; Sv += w2.y * (float)p2.y;
    Sm += w3.x * (float)p3.x; Sv += w3.y * (float)p3.y;
  }
  for (; j < c; j++) {
    int d = csr[start + j];
    float2 w = dd[d];
    h2 p = __builtin_bit_cast(h2, Mcat[(size_t)d * 64 + lane]);
    Sm += w.x * (float)p.x;
    Sv += w.y * (float)p.y;
  }
  float mean = wr.x * Sm;
  float var = wr.y * Sv;
  float o = mean + sample[(size_t)r * 64 + lane] * sqrtf(var);
  float mx = o;
#pragma unroll
  for (int off = 32; off; off >>= 1) mx = fmaxf(mx, __shfl_xor(mx, off, 64));
  float ex = __expf(o - mx);
  float s = ex;
#pragma unroll
  for (int off = 32; off; off >>= 1) s += __shfl_xor(s, off, 64);
  out[(size_t)r * 64 + lane] = o - mx - logf(s);
}

// ---------------- launch ----------------
extern "C" void kernel_launch(void* const* d_in, const int* in_sizes, int n_in,
                              void* d_out, int out_size, void* d_ws, size_t ws_size,
                              hipStream_t stream) {
  (void)n_in; (void)out_size; (void)ws_size;
  const float* x    = (const float*)d_in[0];
  const float* Wm0  = (const float*)d_in[1];
  const float* bm0  = (const float*)d_in[2];
  const float* Wv0  = (const float*)d_in[3];
  const float* bv0  = (const float*)d_in[4];
  const float* Wm1  = (const float*)d_in[5];
  const float* bm1  = (const float*)d_in[6];
  const float* Wv1  = (const float*)d_in[7];
  const float* bv1  = (const float*)d_in[8];
  const float* sample = (const float*)d_in[9];
  const int* esrc   = (const int*)d_in[10];
  const int* edst   = (const int*)d_in[11];
  float* out = (float*)d_out;

  const int N = in_sizes[0] / 512;
  const int E = in_sizes[10];
  const int NBUCK = (N + 63) / 64;

  uint8_t* p = (uint8_t*)d_ws;
  size_t off = 0;
  auto alloc = [&](size_t bytes) -> void* {
    void* r = p + off;
    off += (bytes + 255) & ~(size_t)255;
    return r;
  };
  _Float16* W1t  = (_Float16*)alloc((size_t)512 * 512 * 2);
  _Float16* W2t  = (_Float16*)alloc((size_t)128 * 512 * 2);
  _Float16* Hcat = (_Float16*)alloc((size_t)N * 512 * 2);
  uint32*   Mcat = (uint32*)alloc((size_t)N * 64 * 4);
  int*   cnt    = (int*)alloc((size_t)N * 4);
  float2* dd    = (float2*)alloc((size_t)N * 8);
  int*   rs     = (int*)alloc((size_t)N * 4);
  int*   bcur   = (int*)alloc((size_t)NBUCK * 4);
  int*   bsum   = (int*)alloc(2048);
  int*   boff   = (int*)alloc(2048);
  int*   csr    = (int*)alloc((size_t)(E + 4 * N) * 4);  // padded rows
  // pairs is only live between partB and partC, before gemm1 writes Hcat:
  int2* pairs = (int2*)Hcat;  // needs (E+4N)*8 = 28.8MB <= Hcat's 102.4MB

  hipMemsetAsync(cnt, 0, (size_t)N * 4, stream);

  const int nbN = (N + 255) / 256;
  const int nbE = (E + 255) / 256;

  prep_w_k<<<(512 * 512 + 255) / 256, 256, 0, stream>>>(Wm0, Wv0, Wm1, Wv1, W1t, W2t);
  deg_count_k<<<nbE, 256, 0, stream>>>(esrc, E, cnt);
  deg_fin_k<<<nbN, 256, 0, stream>>>(cnt, dd, N);
  scan1_k<<<nbN, 256, 0, stream>>>(cnt, rs, bsum, N);
  scan2_k<<<1, 512, 0, stream>>>(bsum, boff, nbN);
  scan3_k<<<nbN, 256, 0, stream>>>(rs, boff, N);
  bcur_init_k<<<(NBUCK + 255) / 256, 256, 0, stream>>>(rs, bcur, NBUCK);
  partB_k<<<nbE, 256, 0, stream>>>(esrc, edst, bcur, pairs, E);
  partC_k<<<NBUCK, 256, 0, stream>>>(pairs, rs, cnt, csr, N);

  const int mtiles = (N + 127) / 128;
  gemm1_k<<<mtiles * 4, 256, 0, stream>>>(x, W1t, bm0, bv0, Hcat, N, 512);
  gemm2_k<<<mtiles, 256, 0, stream>>>(Hcat, W2t, bm1, bv1, Mcat, N, 512);
  spmm_final_k<<<(N + 3) / 4, 256, 0, stream>>>(Mcat, dd, rs, cnt, csr, sample, out, N);
}

// Round 4
// 832.619 us; speedup vs baseline: 1.5435x; 1.5435x over previous
//
#include <hip/hip_runtime.h>
#include <cstdint>
#include <cstddef>

// RobustGCN forward on MI355X.
// Pipeline:
//   1. graph prep — deterministic bucket sort (bucket = src>>7, 128 nodes/bucket),
//      NO global atomics anywhere:
//        hist_k:   per-edge-chunk LDS histogram -> h[blk][b]
//        btotal/bscan/boff: scans -> off[blk][b] = private contiguous slice
//        bscatter: edges -> (psrc,pdst) bucket-sorted via LDS cursors
//        countN:   per-node degree from psrc (LDS) -> cnt
//        scans ->  padded CSR row starts rs (16B-aligned rows)
//        partC:    per-bucket scatter pdst into its ~16KB L2-resident CSR region
//   2. GEMM1 (f16 MFMA): Hcat = [elu(x@Wm0+bm0) | relu(x@Wv0+bv0)]  (N x 512)
//   3. GEMM2 (f16 MFMA, block-diag W) with fused attention epilogue ->
//        Mcat[r][c] = pack_h2(m*exp(-v), v*exp(-2v))
//   4. fused dual SpMM (CSR, wave/node, lane/class, 4-edge int4 batches)
//      + sample*sqrt(var) + log_softmax

typedef _Float16 h8 __attribute__((ext_vector_type(8)));
typedef _Float16 h2 __attribute__((ext_vector_type(2)));
typedef float f32x4 __attribute__((ext_vector_type(4)));
typedef unsigned int uint32;

#define BSHIFT 7              // 128 nodes per bucket
#define NCHUNK 256            // edge chunks (blocks) in sort passes

static __device__ __forceinline__ float elu_f(float z) {
  return z > 0.f ? z : expm1f(z);
}

// ---------------- bucket sort ----------------
__global__ __launch_bounds__(256) void hist_k(const int* __restrict__ esrc, int E,
                                              int chunk, int* __restrict__ h, int NB) {
  __shared__ int sh[1024];
  int t = threadIdx.x;
  for (int i = t; i < NB; i += 256) sh[i] = 0;
  __syncthreads();
  int e0 = blockIdx.x * chunk;
  int e1 = min(e0 + chunk, E);
  for (int e = e0 + t; e < e1; e += 256) atomicAdd(&sh[esrc[e] >> BSHIFT], 1);
  __syncthreads();
  for (int i = t; i < NB; i += 256) h[blockIdx.x * NB + i] = sh[i];
}

__global__ __launch_bounds__(256) void btotal_k(const int* __restrict__ h,
                                                int* __restrict__ tot, int NB) {
  int b = blockIdx.x, t = threadIdx.x;
  int v = h[t * NB + b];
#pragma unroll
  for (int off = 32; off; off >>= 1) v += __shfl_xor(v, off, 64);
  __shared__ int sw[4];
  if ((t & 63) == 0) sw[t >> 6] = v;
  __syncthreads();
  if (t == 0) tot[b] = sw[0] + sw[1] + sw[2] + sw[3];
}

__global__ __launch_bounds__(1024) void bscan_k(const int* __restrict__ tot,
                                                int* __restrict__ base, int NB) {
  __shared__ int sh[1024];
  int t = threadIdx.x;
  int v = (t < NB) ? tot[t] : 0;
  sh[t] = v;
  __syncthreads();
  for (int off = 1; off < 1024; off <<= 1) {
    int add = (t >= off) ? sh[t - off] : 0;
    __syncthreads();
    sh[t] += add;
    __syncthreads();
  }
  if (t < NB) base[t] = sh[t] - v;
  if (t == 1023) base[NB] = sh[1023];
}

__global__ __launch_bounds__(256) void boff_k(int* __restrict__ h,
                                              const int* __restrict__ base, int NB) {
  __shared__ int sh[256];
  int b = blockIdx.x, t = threadIdx.x;
  int v = h[t * NB + b];
  sh[t] = v;
  __syncthreads();
  for (int off = 1; off < 256; off <<= 1) {
    int add = (t >= off) ? sh[t - off] : 0;
    __syncthreads();
    sh[t] += add;
    __syncthreads();
  }
  h[t * NB + b] = base[b] + sh[t] - v;
}

__global__ __launch_bounds__(256) void bscatter_k(
    const int* __restrict__ esrc, const int* __restrict__ edst, int E, int chunk,
    const int* __restrict__ h, int* __restrict__ psrc, int* __restrict__ pdst, int NB) {
  __shared__ int lcur[1024];
  int t = threadIdx.x;
  for (int i = t; i < NB; i += 256) lcur[i] = h[blockIdx.x * NB + i];
  __syncthreads();
  int e0 = blockIdx.x * chunk;
  int e1 = min(e0 + chunk, E);
  for (int e = e0 + t; e < e1; e += 256) {
    int s = esrc[e], d = edst[e];
    int pos = atomicAdd(&lcur[s >> BSHIFT], 1);
    psrc[pos] = s;
    pdst[pos] = d;
  }
}

__global__ __launch_bounds__(256) void countN_k(
    const int* __restrict__ psrc, const int* __restrict__ base,
    int* __restrict__ cnt, int n) {
  __shared__ int c128[128];
  int b = blockIdx.x, t = threadIdx.x;
  if (t < 128) c128[t] = 0;
  __syncthreads();
  int lo = base[b], hi = base[b + 1];
  for (int i = lo + t; i < hi; i += 256) atomicAdd(&c128[psrc[i] & 127], 1);
  __syncthreads();
  if (t < 128) {
    int node = b * 128 + t;
    if (node < n) cnt[node] = c128[t];
  }
}

__global__ __launch_bounds__(256) void partC_k(
    const int* __restrict__ psrc, const int* __restrict__ pdst,
    const int* __restrict__ base, const int* __restrict__ rs,
    int* __restrict__ csr, int n) {
  __shared__ int lcur[128];
  int b = blockIdx.x, t = threadIdx.x;
  if (t < 128) {
    int node = b * 128 + t;
    lcur[t] = (node < n) ? rs[node] : 0;
  }
  __syncthreads();
  int lo = base[b], hi = base[b + 1];
  for (int i = lo + t; i < hi; i += 256) {
    int pos = atomicAdd(&lcur[psrc[i] & 127], 1);
    csr[pos] = pdst[i];
  }
}

// ---------------- degree weights + padded row-start scan ----------------
__global__ void deg_fin_k(const int* __restrict__ cnt, float2* __restrict__ dd, int n) {
  int v = blockIdx.x * 256 + threadIdx.x;
  if (v < n) {
    float d = (float)(cnt[v] + 1);  // +1 self loop
    dd[v] = make_float2(rsqrtf(d), 1.f / d);
  }
}

// exclusive scan of PADDED counts ((cnt+3)&~3) so every CSR row start is 16B-aligned
__global__ void scan1_k(const int* __restrict__ cnt, int* __restrict__ excl,
                        int* __restrict__ bsum, int n) {
  __shared__ int sh[256];
  int t = threadIdx.x, idx = blockIdx.x * 256 + t;
  int v = (idx < n) ? ((cnt[idx] + 3) & ~3) : 0;
  sh[t] = v;
  __syncthreads();
  for (int off = 1; off < 256; off <<= 1) {
    int add = (t >= off) ? sh[t - off] : 0;
    __syncthreads();
    sh[t] += add;
    __syncthreads();
  }
  if (idx < n) excl[idx] = sh[t] - v;
  if (t == 255) bsum[blockIdx.x] = sh[255];
}

__global__ void scan2_k(const int* __restrict__ bsum, int* __restrict__ boff, int nb) {
  __shared__ int sh[512];
  int t = threadIdx.x;
  int v = (t < nb) ? bsum[t] : 0;
  sh[t] = v;
  __syncthreads();
  for (int off = 1; off < 512; off <<= 1) {
    int add = (t >= off) ? sh[t - off] : 0;
    __syncthreads();
    sh[t] += add;
    __syncthreads();
  }
  if (t < nb) boff[t] = sh[t] - v;
}

__global__ void scan3_k(int* __restrict__ excl, const int* __restrict__ boff, int n) {
  int idx = blockIdx.x * 256 + threadIdx.x;
  if (idx < n) excl[idx] += boff[blockIdx.x];
}

// ---------------- weight prep: transpose + f16 + fuse ----------------
__global__ void prep_w_k(const float* __restrict__ Wm0, const float* __restrict__ Wv0,
                         const float* __restrict__ Wm1, const float* __restrict__ Wv1,
                         _Float16* __restrict__ W1t, _Float16* __restrict__ W2t) {
  int idx = blockIdx.x * 256 + threadIdx.x;
  if (idx < 512 * 512) {
    int n = idx >> 9, k = idx & 511;
    float v = (n < 256) ? Wm0[k * 256 + n] : Wv0[k * 256 + (n - 256)];
    W1t[idx] = (_Float16)v;
  }
  if (idx < 128 * 512) {
    int n = idx >> 9, k = idx & 511;
    float v = 0.f;
    if (n < 64) { if (k < 256) v = Wm1[k * 64 + n]; }
    else        { if (k >= 256) v = Wv1[(k - 256) * 64 + (n - 64)]; }
    W2t[idx] = (_Float16)v;
  }
}

// ---------------- GEMM1: Hcat = act(x @ W1t^T + b) ----------------
__global__ __launch_bounds__(256) void gemm1_k(
    const float* __restrict__ A, const _Float16* __restrict__ Bt,
    const float* __restrict__ b0, const float* __restrict__ b1,
    _Float16* __restrict__ out, int M, int K) {
  __shared__ _Float16 As[128 * 40];
  __shared__ _Float16 Bs[128 * 40];
  const int bid = blockIdx.x;
  const int mt = bid >> 2, nt = bid & 3;  // nt inner -> A-tile L2/L3 reuse
  const int m0 = mt * 128, n0 = nt * 128;
  const int t = threadIdx.x;
  const int lane = t & 63;
  const int wave = t >> 6;
  const int wm = wave >> 1, wn = wave & 1;
  const int lr = lane & 15, quad = lane >> 4;

  f32x4 acc[4][4] = {};

  for (int kt = 0; kt < K; kt += 32) {
#pragma unroll
    for (int i = 0; i < 2; i++) {
      int c = t + i * 256;
      int row = c >> 2, kc = (c & 3) * 8;
      int gr = m0 + row;
      if (gr > M - 1) gr = M - 1;
      const float* srcf = A + (size_t)gr * K + kt + kc;
      float4 f0 = ((const float4*)srcf)[0];
      float4 f1 = ((const float4*)srcf)[1];
      *(h8*)&As[row * 40 + kc] =
          h8{(_Float16)f0.x, (_Float16)f0.y, (_Float16)f0.z, (_Float16)f0.w,
             (_Float16)f1.x, (_Float16)f1.y, (_Float16)f1.z, (_Float16)f1.w};
      *(h8*)&Bs[row * 40 + kc] =
          *(const h8*)(Bt + (size_t)(n0 + row) * K + kt + kc);
    }
    __syncthreads();
    h8 af[4], bf[4];
#pragma unroll
    for (int i = 0; i < 4; i++)
      af[i] = *(h8*)&As[(wm * 64 + i * 16 + lr) * 40 + quad * 8];
#pragma unroll
    for (int j = 0; j < 4; j++)
      bf[j] = *(h8*)&Bs[(wn * 64 + j * 16 + lr) * 40 + quad * 8];
#pragma unroll
    for (int i = 0; i < 4; i++)
#pragma unroll
      for (int j = 0; j < 4; j++)
        acc[i][j] = __builtin_amdgcn_mfma_f32_16x16x32_f16(af[i], bf[j], acc[i][j], 0, 0, 0);
    __syncthreads();
  }

#pragma unroll
  for (int j = 0; j < 4; j++) {
    int gc = n0 + wn * 64 + j * 16 + lr;
    float bj = (gc < 256) ? b0[gc] : b1[gc - 256];
#pragma unroll
    for (int i = 0; i < 4; i++) {
#pragma unroll
      for (int r = 0; r < 4; r++) {
        int gr = m0 + wm * 64 + i * 16 + quad * 4 + r;
        if (gr < M) {
          float z = acc[i][j][r] + bj;
          float v = (gc < 256) ? elu_f(z) : fmaxf(z, 0.f);
          out[(size_t)gr * 512 + gc] = (_Float16)v;
        }
      }
    }
  }
}

// ---------------- GEMM2 + fused attention ----------------
__global__ __launch_bounds__(256) void gemm2_k(
    const _Float16* __restrict__ A, const _Float16* __restrict__ Bt,
    const float* __restrict__ bm1, const float* __restrict__ bv1,
    uint32* __restrict__ Mcat, int M, int K) {
  __shared__ _Float16 As[128 * 40];
  __shared__ _Float16 Bs[128 * 40];
  const int m0 = blockIdx.x * 128;
  const int t = threadIdx.x;
  const int lane = t & 63;
  const int wave = t >> 6;
  const int lr = lane & 15, quad = lane >> 4;

  f32x4 acc[2][8] = {};

  for (int kt = 0; kt < K; kt += 32) {
#pragma unroll
    for (int i = 0; i < 2; i++) {
      int c = t + i * 256;
      int row = c >> 2, kc = (c & 3) * 8;
      int gr = m0 + row;
      if (gr > M - 1) gr = M - 1;
      *(h8*)&As[row * 40 + kc] = *(const h8*)(A + (size_t)gr * K + kt + kc);
      *(h8*)&Bs[row * 40 + kc] = *(const h8*)(Bt + (size_t)row * K + kt + kc);
    }
    __syncthreads();
    h8 af[2], bf[8];
#pragma unroll
    for (int i = 0; i < 2; i++)
      af[i] = *(h8*)&As[(wave * 32 + i * 16 + lr) * 40 + quad * 8];
#pragma unroll
    for (int j = 0; j < 8; j++)
      bf[j] = *(h8*)&Bs[(j * 16 + lr) * 40 + quad * 8];
#pragma unroll
    for (int i = 0; i < 2; i++)
#pragma unroll
      for (int j = 0; j < 8; j++)
        acc[i][j] = __builtin_amdgcn_mfma_f32_16x16x32_f16(af[i], bf[j], acc[i][j], 0, 0, 0);
    __syncthreads();
  }

#pragma unroll
  for (int jm = 0; jm < 4; jm++) {
    int c = jm * 16 + lr;                 // class col 0..63
    float bm = bm1[c], bv = bv1[c];
#pragma unroll
    for (int i = 0; i < 2; i++) {
#pragma unroll
      for (int r = 0; r < 4; r++) {
        int gr = m0 + wave * 32 + i * 16 + quad * 4 + r;
        if (gr < M) {
          float zm = acc[i][jm][r] + bm;
          float zv = acc[i][4 + jm][r] + bv;
          float m = elu_f(zm);
          float v = fmaxf(zv, 0.f) + 1e-6f;
          float a = __expf(-v);
          h2 pk;
          pk.x = (_Float16)(m * a);       // mean*attn
          pk.y = (_Float16)(v * a * a);   // var*attn^2
          Mcat[(size_t)gr * 64 + c] = __builtin_bit_cast(uint32, pk);
        }
      }
    }
  }
}

// ---------------- fused dual SpMM + reparam + log_softmax ----------------
__global__ __launch_bounds__(256) void spmm_final_k(
    const uint32* __restrict__ Mcat, const float2* __restrict__ dd,
    const int* __restrict__ row_start, const int* __restrict__ cnt,
    const int* __restrict__ csr, const float* __restrict__ sample,
    float* __restrict__ out, int n) {
  int wid = threadIdx.x >> 6, lane = threadIdx.x & 63;
  int r = blockIdx.x * 4 + wid;
  if (r >= n) return;
  float2 wr = dd[r];
  h2 self = __builtin_bit_cast(h2, Mcat[(size_t)r * 64 + lane]);
  float Sm = wr.x * (float)self.x;
  float Sv = wr.y * (float)self.y;
  int start = __builtin_amdgcn_readfirstlane(row_start[r]);
  int c = __builtin_amdgcn_readfirstlane(cnt[r]);
  int j = 0;
  for (; j + 4 <= c; j += 4) {
    int4 d4 = *(const int4*)(csr + start + j);
    float2 w0 = dd[d4.x];
    float2 w1 = dd[d4.y];
    float2 w2 = dd[d4.z];
    float2 w3 = dd[d4.w];
    h2 p0 = __builtin_bit_cast(h2, Mcat[(size_t)d4.x * 64 + lane]);
    h2 p1 = __builtin_bit_cast(h2, Mcat[(size_t)d4.y * 64 + lane]);
    h2 p2 = __builtin_bit_cast(h2, Mcat[(size_t)d4.z * 64 + lane]);
    h2 p3 = __builtin_bit_cast(h2, Mcat[(size_t)d4.w * 64 + lane]);
    Sm += w0.x * (float)p0.x; Sv += w0.y * (float)p0.y;
    Sm += w1.x * (float)p1.x; Sv += w1.y * (float)p1.y;
    Sm += w2.x * (float)p2.x; Sv += w2.y * (float)p2.y;
    Sm += w3.x * (float)p3.x; Sv += w3.y * (float)p3.y;
  }
  for (; j < c; j++) {
    int d = csr[start + j];
    float2 w = dd[d];
    h2 p = __builtin_bit_cast(h2, Mcat[(size_t)d * 64 + lane]);
    Sm += w.x * (float)p.x;
    Sv += w.y * (float)p.y;
  }
  float mean = wr.x * Sm;
  float var = wr.y * Sv;
  float o = mean + sample[(size_t)r * 64 + lane] * sqrtf(var);
  float mx = o;
#pragma unroll
  for (int off = 32; off; off >>= 1) mx = fmaxf(mx, __shfl_xor(mx, off, 64));
  float ex = __expf(o - mx);
  float s = ex;
#pragma unroll
  for (int off = 32; off; off >>= 1) s += __shfl_xor(s, off, 64);
  out[(size_t)r * 64 + lane] = o - mx - logf(s);
}

// ---------------- launch ----------------
extern "C" void kernel_launch(void* const* d_in, const int* in_sizes, int n_in,
                              void* d_out, int out_size, void* d_ws, size_t ws_size,
                              hipStream_t stream) {
  (void)n_in; (void)out_size; (void)ws_size;
  const float* x    = (const float*)d_in[0];
  const float* Wm0  = (const float*)d_in[1];
  const float* bm0  = (const float*)d_in[2];
  const float* Wv0  = (const float*)d_in[3];
  const float* bv0  = (const float*)d_in[4];
  const float* Wm1  = (const float*)d_in[5];
  const float* bm1  = (const float*)d_in[6];
  const float* Wv1  = (const float*)d_in[7];
  const float* bv1  = (const float*)d_in[8];
  const float* sample = (const float*)d_in[9];
  const int* esrc   = (const int*)d_in[10];
  const int* edst   = (const int*)d_in[11];
  float* out = (float*)d_out;

  const int N = in_sizes[0] / 512;
  const int E = in_sizes[10];
  const int NB = (N + 127) >> BSHIFT;          // 128-node buckets (<=1024 for N<=131072)
  const int chunk = (E + NCHUNK - 1) / NCHUNK;

  uint8_t* p = (uint8_t*)d_ws;
  size_t off = 0;
  auto alloc = [&](size_t bytes) -> void* {
    void* r = p + off;
    off += (bytes + 255) & ~(size_t)255;
    return r;
  };
  _Float16* W1t  = (_Float16*)alloc((size_t)512 * 512 * 2);
  _Float16* W2t  = (_Float16*)alloc((size_t)128 * 512 * 2);
  _Float16* Hcat = (_Float16*)alloc((size_t)N * 512 * 2);
  uint32*   Mcat = (uint32*)alloc((size_t)N * 64 * 4);
  int*   cnt    = (int*)alloc((size_t)N * 4);
  float2* dd    = (float2*)alloc((size_t)N * 8);
  int*   rs     = (int*)alloc((size_t)N * 4);
  int*   h      = (int*)alloc((size_t)NCHUNK * NB * 4);
  int*   tot    = (int*)alloc((size_t)(NB + 1) * 4);
  int*   base   = (int*)alloc((size_t)(NB + 1) * 4);
  int*   bsum   = (int*)alloc(2048);
  int*   boff   = (int*)alloc(2048);
  int*   csr    = (int*)alloc((size_t)(E + 4 * N) * 4);  // padded rows
  // bucket-sorted edge arrays are only live before gemm1 writes Hcat:
  int* psrc = (int*)Hcat;        // E ints
  int* pdst = psrc + E;          // E ints  (2E*4 = 25.6MB <= Hcat's 102.4MB)

  const int nbN = (N + 255) / 256;

  prep_w_k<<<(512 * 512 + 255) / 256, 256, 0, stream>>>(Wm0, Wv0, Wm1, Wv1, W1t, W2t);
  // bucket sort (no global atomics)
  hist_k<<<NCHUNK, 256, 0, stream>>>(esrc, E, chunk, h, NB);
  btotal_k<<<NB, 256, 0, stream>>>(h, tot, NB);
  bscan_k<<<1, 1024, 0, stream>>>(tot, base, NB);
  boff_k<<<NB, 256, 0, stream>>>(h, base, NB);
  bscatter_k<<<NCHUNK, 256, 0, stream>>>(esrc, edst, E, chunk, h, psrc, pdst, NB);
  countN_k<<<NB, 256, 0, stream>>>(psrc, base, cnt, N);
  // degree weights + padded row starts
  deg_fin_k<<<nbN, 256, 0, stream>>>(cnt, dd, N);
  scan1_k<<<nbN, 256, 0, stream>>>(cnt, rs, bsum, N);
  scan2_k<<<1, 512, 0, stream>>>(bsum, boff, nbN);
  scan3_k<<<nbN, 256, 0, stream>>>(rs, boff, N);
  partC_k<<<NB, 256, 0, stream>>>(psrc, pdst, base, rs, csr, N);

  const int mtiles = (N + 127) / 128;
  gemm1_k<<<mtiles * 4, 256, 0, stream>>>(x, W1t, bm0, bv0, Hcat, N, 512);
  gemm2_k<<<mtiles, 256, 0, stream>>>(Hcat, W2t, bm1, bv1, Mcat, N, 512);
  spmm_final_k<<<(N + 3) / 4, 256, 0, stream>>>(Mcat, dd, rs, cnt, csr, sample, out, N);
}

// Round 5
// 762.549 us; speedup vs baseline: 1.6853x; 1.0919x over previous
//
#include <hip/hip_runtime.h>
#include <cstdint>
#include <cstddef>

// RobustGCN forward on MI355X.
//   1. graph prep — deterministic bucket sort (bucket = src>>7), no global atomics:
//      hist -> btotal/bscan/boff -> bscatter(int2 pairs) -> countN(+deg weights)
//      -> padded scans -> partC (per-bucket CSR scatter via LDS cursors)
//   2. GEMM1 (f16 MFMA, reg-prefetch double-buffered LDS, XCD-swizzled grid):
//      Hcat = [elu(x@Wm0+bm0) | relu(x@Wv0+bv0)]  (N x 512), LDS-transposed epilogue
//   3. GEMM2 (f16 MFMA, reg-dbuf, block-diag W) + fused attention epilogue ->
//      Mcat[r][c] = pack_h2(m*exp(-v), v*exp(-2v))
//   4. fused dual SpMM (CSR, wave/node, lane/class, int4 edge batches)
//      + sample*sqrt(var) + log_softmax

typedef _Float16 h8 __attribute__((ext_vector_type(8)));
typedef _Float16 h2 __attribute__((ext_vector_type(2)));
typedef float f32x4 __attribute__((ext_vector_type(4)));
typedef unsigned int uint32;

#define BSHIFT 7              // 128 nodes per bucket
#define NCHUNK 256            // edge chunks (blocks) in sort passes

static __device__ __forceinline__ float elu_f(float z) {
  return z > 0.f ? z : expm1f(z);
}

// ---------------- bucket sort ----------------
__global__ __launch_bounds__(256) void hist_k(const int* __restrict__ esrc, int E,
                                              int chunk, int* __restrict__ h, int NB) {
  __shared__ int sh[1024];
  int t = threadIdx.x;
  for (int i = t; i < NB; i += 256) sh[i] = 0;
  __syncthreads();
  int e0 = blockIdx.x * chunk;
  int e1 = min(e0 + chunk, E);
  for (int e = e0 + t; e < e1; e += 256) atomicAdd(&sh[esrc[e] >> BSHIFT], 1);
  __syncthreads();
  for (int i = t; i < NB; i += 256) h[blockIdx.x * NB + i] = sh[i];
}

__global__ __launch_bounds__(256) void btotal_k(const int* __restrict__ h,
                                                int* __restrict__ tot, int NB) {
  int b = blockIdx.x, t = threadIdx.x;
  int v = h[t * NB + b];
#pragma unroll
  for (int off = 32; off; off >>= 1) v += __shfl_xor(v, off, 64);
  __shared__ int sw[4];
  if ((t & 63) == 0) sw[t >> 6] = v;
  __syncthreads();
  if (t == 0) tot[b] = sw[0] + sw[1] + sw[2] + sw[3];
}

__global__ __launch_bounds__(1024) void bscan_k(const int* __restrict__ tot,
                                                int* __restrict__ base, int NB) {
  __shared__ int sh[1024];
  int t = threadIdx.x;
  int v = (t < NB) ? tot[t] : 0;
  sh[t] = v;
  __syncthreads();
  for (int off = 1; off < 1024; off <<= 1) {
    int add = (t >= off) ? sh[t - off] : 0;
    __syncthreads();
    sh[t] += add;
    __syncthreads();
  }
  if (t < NB) base[t] = sh[t] - v;
  if (t == 1023) base[NB] = sh[1023];
}

__global__ __launch_bounds__(256) void boff_k(int* __restrict__ h,
                                              const int* __restrict__ base, int NB) {
  __shared__ int sh[256];
  int b = blockIdx.x, t = threadIdx.x;
  int v = h[t * NB + b];
  sh[t] = v;
  __syncthreads();
  for (int off = 1; off < 256; off <<= 1) {
    int add = (t >= off) ? sh[t - off] : 0;
    __syncthreads();
    sh[t] += add;
    __syncthreads();
  }
  h[t * NB + b] = base[b] + sh[t] - v;
}

__global__ __launch_bounds__(256) void bscatter_k(
    const int* __restrict__ esrc, const int* __restrict__ edst, int E, int chunk,
    const int* __restrict__ h, int2* __restrict__ pairs, int NB) {
  __shared__ int lcur[1024];
  int t = threadIdx.x;
  for (int i = t; i < NB; i += 256) lcur[i] = h[blockIdx.x * NB + i];
  __syncthreads();
  int e0 = blockIdx.x * chunk;
  int e1 = min(e0 + chunk, E);
  for (int e = e0 + t; e < e1; e += 256) {
    int s = esrc[e], d = edst[e];
    int pos = atomicAdd(&lcur[s >> BSHIFT], 1);
    pairs[pos] = make_int2(s, d);
  }
}

// per-node degree (bucket sort makes per-bucket counts complete) + degree weights
__global__ __launch_bounds__(256) void countN_k(
    const int2* __restrict__ pairs, const int* __restrict__ base,
    int* __restrict__ cnt, float2* __restrict__ dd, int n) {
  __shared__ int c128[128];
  int b = blockIdx.x, t = threadIdx.x;
  if (t < 128) c128[t] = 0;
  __syncthreads();
  int lo = base[b], hi = base[b + 1];
  for (int i = lo + t; i < hi; i += 256) atomicAdd(&c128[pairs[i].x & 127], 1);
  __syncthreads();
  if (t < 128) {
    int node = b * 128 + t;
    if (node < n) {
      int c = c128[t];
      cnt[node] = c;
      float d = (float)(c + 1);  // +1 self loop
      dd[node] = make_float2(rsqrtf(d), 1.f / d);
    }
  }
}

__global__ __launch_bounds__(256) void partC_k(
    const int2* __restrict__ pairs, const int* __restrict__ base,
    const int* __restrict__ rs, int* __restrict__ csr, int n) {
  __shared__ int lcur[128];
  int b = blockIdx.x, t = threadIdx.x;
  if (t < 128) {
    int node = b * 128 + t;
    lcur[t] = (node < n) ? rs[node] : 0;
  }
  __syncthreads();
  int lo = base[b], hi = base[b + 1];
  for (int i = lo + t; i < hi; i += 256) {
    int2 pr = pairs[i];
    int pos = atomicAdd(&lcur[pr.x & 127], 1);
    csr[pos] = pr.y;
  }
}

// ---------------- padded row-start scan ----------------
// exclusive scan of PADDED counts ((cnt+3)&~3) so every CSR row start is 16B-aligned
__global__ void scan1_k(const int* __restrict__ cnt, int* __restrict__ excl,
                        int* __restrict__ bsum, int n) {
  __shared__ int sh[256];
  int t = threadIdx.x, idx = blockIdx.x * 256 + t;
  int v = (idx < n) ? ((cnt[idx] + 3) & ~3) : 0;
  sh[t] = v;
  __syncthreads();
  for (int off = 1; off < 256; off <<= 1) {
    int add = (t >= off) ? sh[t - off] : 0;
    __syncthreads();
    sh[t] += add;
    __syncthreads();
  }
  if (idx < n) excl[idx] = sh[t] - v;
  if (t == 255) bsum[blockIdx.x] = sh[255];
}

__global__ void scan2_k(const int* __restrict__ bsum, int* __restrict__ boff, int nb) {
  __shared__ int sh[512];
  int t = threadIdx.x;
  int v = (t < nb) ? bsum[t] : 0;
  sh[t] = v;
  __syncthreads();
  for (int off = 1; off < 512; off <<= 1) {
    int add = (t >= off) ? sh[t - off] : 0;
    __syncthreads();
    sh[t] += add;
    __syncthreads();
  }
  if (t < nb) boff[t] = sh[t] - v;
}

__global__ void scan3_k(int* __restrict__ excl, const int* __restrict__ boff, int n) {
  int idx = blockIdx.x * 256 + threadIdx.x;
  if (idx < n) excl[idx] += boff[blockIdx.x];
}

// ---------------- weight prep: transpose + f16 + fuse ----------------
__global__ void prep_w_k(const float* __restrict__ Wm0, const float* __restrict__ Wv0,
                         const float* __restrict__ Wm1, const float* __restrict__ Wv1,
                         _Float16* __restrict__ W1t, _Float16* __restrict__ W2t) {
  int idx = blockIdx.x * 256 + threadIdx.x;
  if (idx < 512 * 512) {
    int n = idx >> 9, k = idx & 511;
    float v = (n < 256) ? Wm0[k * 256 + n] : Wv0[k * 256 + (n - 256)];
    W1t[idx] = (_Float16)v;
  }
  if (idx < 128 * 512) {
    int n = idx >> 9, k = idx & 511;
    float v = 0.f;
    if (n < 64) { if (k < 256) v = Wm1[k * 64 + n]; }
    else        { if (k >= 256) v = Wv1[(k - 256) * 64 + (n - 64)]; }
    W2t[idx] = (_Float16)v;
  }
}

// ---------------- GEMM1: Hcat = act(x @ W1t^T + b) ----------------
// BM=BN=128, BK=32, 4 waves (2x2), reg-prefetch double-buffered LDS, 1 barrier/iter.
// Grid swizzle: supergroups of 8 mt; 4 nt-blocks sharing an mt are 8 apart in
// dispatch order -> same XCD (bid%8 mapping) -> A-tile fetched from HBM once.
__global__ __launch_bounds__(256) void gemm1_k(
    const float* __restrict__ A, const _Float16* __restrict__ Bt,
    const float* __restrict__ b0, const float* __restrict__ b1,
    _Float16* __restrict__ out, int M, int K, int mtiles) {
  __shared__ _Float16 lds[20480];       // 40 KB: As[2][5120] | Bs[2][5120]
  _Float16* As = lds;
  _Float16* Bs = lds + 10240;

  const int sg = blockIdx.x >> 5, loc = blockIdx.x & 31;
  const int nt = loc >> 3, mtl = loc & 7;
  const int mt = sg * 8 + mtl;
  if (mt >= mtiles) return;
  const int m0 = mt * 128, n0 = nt * 128;
  const int t = threadIdx.x;
  const int lane = t & 63;
  const int wave = t >> 6;
  const int wm = wave >> 1, wn = wave & 1;
  const int lr = lane & 15, quad = lane >> 4;
  const int trow = t >> 2;              // 0..63
  const int tkc = (t & 3) * 8;          // 0,8,16,24

  const size_t arow0 = (size_t)min(m0 + trow, M - 1) * K;
  const size_t arow1 = (size_t)min(m0 + trow + 64, M - 1) * K;
  const size_t brow0 = (size_t)(n0 + trow) * K;
  const size_t brow1 = (size_t)(n0 + trow + 64) * K;

  f32x4 acc[4][4] = {};
  float4 pa[2][2];
  h8 pb[2];

  // prologue: load kt=0
  {
    const float* s0 = A + arow0 + tkc;
    const float* s1 = A + arow1 + tkc;
    pa[0][0] = ((const float4*)s0)[0]; pa[0][1] = ((const float4*)s0)[1];
    pa[1][0] = ((const float4*)s1)[0]; pa[1][1] = ((const float4*)s1)[1];
    pb[0] = *(const h8*)(Bt + brow0 + tkc);
    pb[1] = *(const h8*)(Bt + brow1 + tkc);
  }
  // store tile 0 into buf 0
  {
    *(h8*)&As[trow * 40 + tkc] =
        h8{(_Float16)pa[0][0].x, (_Float16)pa[0][0].y, (_Float16)pa[0][0].z, (_Float16)pa[0][0].w,
           (_Float16)pa[0][1].x, (_Float16)pa[0][1].y, (_Float16)pa[0][1].z, (_Float16)pa[0][1].w};
    *(h8*)&As[(trow + 64) * 40 + tkc] =
        h8{(_Float16)pa[1][0].x, (_Float16)pa[1][0].y, (_Float16)pa[1][0].z, (_Float16)pa[1][0].w,
           (_Float16)pa[1][1].x, (_Float16)pa[1][1].y, (_Float16)pa[1][1].z, (_Float16)pa[1][1].w};
    *(h8*)&Bs[trow * 40 + tkc] = pb[0];
    *(h8*)&Bs[(trow + 64) * 40 + tkc] = pb[1];
  }
  __syncthreads();

  for (int kt = 0; kt < K; kt += 32) {
    const int cur = (kt >> 5) & 1;
    const int curo = cur * 5120;
    const bool more = (kt + 32) < K;
    if (more) {
      const float* s0 = A + arow0 + kt + 32 + tkc;
      const float* s1 = A + arow1 + kt + 32 + tkc;
      pa[0][0] = ((const float4*)s0)[0]; pa[0][1] = ((const float4*)s0)[1];
      pa[1][0] = ((const float4*)s1)[0]; pa[1][1] = ((const float4*)s1)[1];
      pb[0] = *(const h8*)(Bt + brow0 + kt + 32 + tkc);
      pb[1] = *(const h8*)(Bt + brow1 + kt + 32 + tkc);
    }
    h8 af[4], bf[4];
#pragma unroll
    for (int i = 0; i < 4; i++)
      af[i] = *(h8*)&As[curo + (wm * 64 + i * 16 + lr) * 40 + quad * 8];
#pragma unroll
    for (int j = 0; j < 4; j++)
      bf[j] = *(h8*)&Bs[curo + (wn * 64 + j * 16 + lr) * 40 + quad * 8];
#pragma unroll
    for (int i = 0; i < 4; i++)
#pragma unroll
      for (int j = 0; j < 4; j++)
        acc[i][j] = __builtin_amdgcn_mfma_f32_16x16x32_f16(af[i], bf[j], acc[i][j], 0, 0, 0);
    if (more) {
      const int nxto = (cur ^ 1) * 5120;
      *(h8*)&As[nxto + trow * 40 + tkc] =
          h8{(_Float16)pa[0][0].x, (_Float16)pa[0][0].y, (_Float16)pa[0][0].z, (_Float16)pa[0][0].w,
             (_Float16)pa[0][1].x, (_Float16)pa[0][1].y, (_Float16)pa[0][1].z, (_Float16)pa[0][1].w};
      *(h8*)&As[nxto + (trow + 64) * 40 + tkc] =
          h8{(_Float16)pa[1][0].x, (_Float16)pa[1][0].y, (_Float16)pa[1][0].z, (_Float16)pa[1][0].w,
             (_Float16)pa[1][1].x, (_Float16)pa[1][1].y, (_Float16)pa[1][1].z, (_Float16)pa[1][1].w};
      *(h8*)&Bs[nxto + trow * 40 + tkc] = pb[0];
      *(h8*)&Bs[nxto + (trow + 64) * 40 + tkc] = pb[1];
      __syncthreads();
    }
  }

  // epilogue: bias+act in regs -> f16 LDS tile (stride 136) -> 16B coalesced stores
  __syncthreads();                       // all waves done with MFMA LDS reads
#pragma unroll
  for (int j = 0; j < 4; j++) {
    int gc = n0 + wn * 64 + j * 16 + lr;
    float bj = (gc < 256) ? b0[gc] : b1[gc - 256];
#pragma unroll
    for (int i = 0; i < 4; i++) {
#pragma unroll
      for (int r = 0; r < 4; r++) {
        float z = acc[i][j][r] + bj;
        float v = (gc < 256) ? elu_f(z) : fmaxf(z, 0.f);
        lds[(wm * 64 + i * 16 + quad * 4 + r) * 136 + wn * 64 + j * 16 + lr] = (_Float16)v;
      }
    }
  }
  __syncthreads();
  {
    const int row = t >> 1, col0 = (t & 1) * 64;
    const int gr = m0 + row;
    if (gr < M) {
      _Float16* dst = out + (size_t)gr * 512 + n0 + col0;
#pragma unroll
      for (int k = 0; k < 8; k++)
        *(h8*)(dst + k * 8) = *(h8*)&lds[row * 136 + col0 + k * 8];
    }
  }
}

// ---------------- GEMM2 + fused attention (reg-dbuf) ----------------
// BM=128, N=128 (cols 0..63 mean, 64..127 var). 4 waves, wave = 32 rows x 8 j-tiles.
__global__ __launch_bounds__(256) void gemm2_k(
    const _Float16* __restrict__ A, const _Float16* __restrict__ Bt,
    const float* __restrict__ bm1, const float* __restrict__ bv1,
    uint32* __restrict__ Mcat, int M, int K) {
  __shared__ _Float16 lds[20480];
  _Float16* As = lds;
  _Float16* Bs = lds + 10240;
  const int m0 = blockIdx.x * 128;
  const int t = threadIdx.x;
  const int lane = t & 63;
  const int wave = t >> 6;
  const int lr = lane & 15, quad = lane >> 4;
  const int trow = t >> 2;
  const int tkc = (t & 3) * 8;

  const size_t arow0 = (size_t)min(m0 + trow, M - 1) * K;
  const size_t arow1 = (size_t)min(m0 + trow + 64, M - 1) * K;
  const size_t brow0 = (size_t)trow * K;
  const size_t brow1 = (size_t)(trow + 64) * K;

  f32x4 acc[2][8] = {};
  h8 pa[2], pb[2];

  pa[0] = *(const h8*)(A + arow0 + tkc);
  pa[1] = *(const h8*)(A + arow1 + tkc);
  pb[0] = *(const h8*)(Bt + brow0 + tkc);
  pb[1] = *(const h8*)(Bt + brow1 + tkc);
  *(h8*)&As[trow * 40 + tkc] = pa[0];
  *(h8*)&As[(trow + 64) * 40 + tkc] = pa[1];
  *(h8*)&Bs[trow * 40 + tkc] = pb[0];
  *(h8*)&Bs[(trow + 64) * 40 + tkc] = pb[1];
  __syncthreads();

  for (int kt = 0; kt < K; kt += 32) {
    const int cur = (kt >> 5) & 1;
    const int curo = cur * 5120;
    const bool more = (kt + 32) < K;
    if (more) {
      pa[0] = *(const h8*)(A + arow0 + kt + 32 + tkc);
      pa[1] = *(const h8*)(A + arow1 + kt + 32 + tkc);
      pb[0] = *(const h8*)(Bt + brow0 + kt + 32 + tkc);
      pb[1] = *(const h8*)(Bt + brow1 + kt + 32 + tkc);
    }
    h8 af[2], bf[8];
#pragma unroll
    for (int i = 0; i < 2; i++)
      af[i] = *(h8*)&As[curo + (wave * 32 + i * 16 + lr) * 40 + quad * 8];
#pragma unroll
    for (int j = 0; j < 8; j++)
      bf[j] = *(h8*)&Bs[curo + (j * 16 + lr) * 40 + quad * 8];
#pragma unroll
    for (int i = 0; i < 2; i++)
#pragma unroll
      for (int j = 0; j < 8; j++)
        acc[i][j] = __builtin_amdgcn_mfma_f32_16x16x32_f16(af[i], bf[j], acc[i][j], 0, 0, 0);
    if (more) {
      const int nxto = (cur ^ 1) * 5120;
      *(h8*)&As[nxto + trow * 40 + tkc] = pa[0];
      *(h8*)&As[nxto + (trow + 64) * 40 + tkc] = pa[1];
      *(h8*)&Bs[nxto + trow * 40 + tkc] = pb[0];
      *(h8*)&Bs[nxto + (trow + 64) * 40 + tkc] = pb[1];
      __syncthreads();
    }
  }

#pragma unroll
  for (int jm = 0; jm < 4; jm++) {
    int c = jm * 16 + lr;                 // class col 0..63
    float bm = bm1[c], bv = bv1[c];
#pragma unroll
    for (int i = 0; i < 2; i++) {
#pragma unroll
      for (int r = 0; r < 4; r++) {
        int gr = m0 + wave * 32 + i * 16 + quad * 4 + r;
        if (gr < M) {
          float zm = acc[i][jm][r] + bm;
          float zv = acc[i][4 + jm][r] + bv;
          float m = elu_f(zm);
          float v = fmaxf(zv, 0.f) + 1e-6f;
          float a = __expf(-v);
          h2 pk;
          pk.x = (_Float16)(m * a);       // mean*attn
          pk.y = (_Float16)(v * a * a);   // var*attn^2
          Mcat[(size_t)gr * 64 + c] = __builtin_bit_cast(uint32, pk);
        }
      }
    }
  }
}

// ---------------- fused dual SpMM + reparam + log_softmax ----------------
__global__ __launch_bounds__(256) void spmm_final_k(
    const uint32* __restrict__ Mcat, const float2* __restrict__ dd,
    const int* __restrict__ row_start, const int* __restrict__ cnt,
    const int* __restrict__ csr, const float* __restrict__ sample,
    float* __restrict__ out, int n) {
  int wid = threadIdx.x >> 6, lane = threadIdx.x & 63;
  int r = blockIdx.x * 4 + wid;
  if (r >= n) return;
  float2 wr = dd[r];
  h2 self = __builtin_bit_cast(h2, Mcat[(size_t)r * 64 + lane]);
  float Sm = wr.x * (float)self.x;
  float Sv = wr.y * (float)self.y;
  int start = __builtin_amdgcn_readfirstlane(row_start[r]);
  int c = __builtin_amdgcn_readfirstlane(cnt[r]);
  int j = 0;
  for (; j + 4 <= c; j += 4) {
    int4 d4 = *(const int4*)(csr + start + j);
    float2 w0 = dd[d4.x];
    float2 w1 = dd[d4.y];
    float2 w2 = dd[d4.z];
    float2 w3 = dd[d4.w];
    h2 p0 = __builtin_bit_cast(h2, Mcat[(size_t)d4.x * 64 + lane]);
    h2 p1 = __builtin_bit_cast(h2, Mcat[(size_t)d4.y * 64 + lane]);
    h2 p2 = __builtin_bit_cast(h2, Mcat[(size_t)d4.z * 64 + lane]);
    h2 p3 = __builtin_bit_cast(h2, Mcat[(size_t)d4.w * 64 + lane]);
    Sm += w0.x * (float)p0.x; Sv += w0.y * (float)p0.y;
    Sm += w1.x * (float)p1.x; Sv += w1.y * (float)p1.y;
    Sm += w2.x * (float)p2.x; Sv += w2.y * (float)p2.y;
    Sm += w3.x * (float)p3.x; Sv += w3.y * (float)p3.y;
  }
  for (; j < c; j++) {
    int d = csr[start + j];
    float2 w = dd[d];
    h2 p = __builtin_bit_cast(h2, Mcat[(size_t)d * 64 + lane]);
    Sm += w.x * (float)p.x;
    Sv += w.y * (float)p.y;
  }
  float mean = wr.x * Sm;
  float var = wr.y * Sv;
  float o = mean + sample[(size_t)r * 64 + lane] * sqrtf(var);
  float mx = o;
#pragma unroll
  for (int off = 32; off; off >>= 1) mx = fmaxf(mx, __shfl_xor(mx, off, 64));
  float ex = __expf(o - mx);
  float s = ex;
#pragma unroll
  for (int off = 32; off; off >>= 1) s += __shfl_xor(s, off, 64);
  out[(size_t)r * 64 + lane] = o - mx - logf(s);
}

// ---------------- launch ----------------
extern "C" void kernel_launch(void* const* d_in, const int* in_sizes, int n_in,
                              void* d_out, int out_size, void* d_ws, size_t ws_size,
                              hipStream_t stream) {
  (void)n_in; (void)out_size; (void)ws_size;
  const float* x    = (const float*)d_in[0];
  const float* Wm0  = (const float*)d_in[1];
  const float* bm0  = (const float*)d_in[2];
  const float* Wv0  = (const float*)d_in[3];
  const float* bv0  = (const float*)d_in[4];
  const float* Wm1  = (const float*)d_in[5];
  const float* bm1  = (const float*)d_in[6];
  const float* Wv1  = (const float*)d_in[7];
  const float* bv1  = (const float*)d_in[8];
  const float* sample = (const float*)d_in[9];
  const int* esrc   = (const int*)d_in[10];
  const int* edst   = (const int*)d_in[11];
  float* out = (float*)d_out;

  const int N = in_sizes[0] / 512;
  const int E = in_sizes[10];
  const int NB = (N + 127) >> BSHIFT;          // 128-node buckets
  const int chunk = (E + NCHUNK - 1) / NCHUNK;

  uint8_t* p = (uint8_t*)d_ws;
  size_t off = 0;
  auto alloc = [&](size_t bytes) -> void* {
    void* r = p + off;
    off += (bytes + 255) & ~(size_t)255;
    return r;
  };
  _Float16* W1t  = (_Float16*)alloc((size_t)512 * 512 * 2);
  _Float16* W2t  = (_Float16*)alloc((size_t)128 * 512 * 2);
  _Float16* Hcat = (_Float16*)alloc((size_t)N * 512 * 2);
  uint32*   Mcat = (uint32*)alloc((size_t)N * 64 * 4);
  int*   cnt    = (int*)alloc((size_t)N * 4);
  float2* dd    = (float2*)alloc((size_t)N * 8);
  int*   rs     = (int*)alloc((size_t)N * 4);
  int*   h      = (int*)alloc((size_t)NCHUNK * NB * 4);
  int*   tot    = (int*)alloc((size_t)(NB + 1) * 4);
  int*   base   = (int*)alloc((size_t)(NB + 1) * 4);
  int*   bsum   = (int*)alloc(2048);
  int*   boff   = (int*)alloc(2048);
  int*   csr    = (int*)alloc((size_t)(E + 4 * N) * 4);  // padded rows
  // bucket-sorted pairs only live before gemm1 writes Hcat:
  int2* pairs = (int2*)Hcat;     // E*8 = 25.6MB <= Hcat's 102.4MB

  const int nbN = (N + 255) / 256;

  prep_w_k<<<(512 * 512 + 255) / 256, 256, 0, stream>>>(Wm0, Wv0, Wm1, Wv1, W1t, W2t);
  hist_k<<<NCHUNK, 256, 0, stream>>>(esrc, E, chunk, h, NB);
  btotal_k<<<NB, 256, 0, stream>>>(h, tot, NB);
  bscan_k<<<1, 1024, 0, stream>>>(tot, base, NB);
  boff_k<<<NB, 256, 0, stream>>>(h, base, NB);
  bscatter_k<<<NCHUNK, 256, 0, stream>>>(esrc, edst, E, chunk, h, pairs, NB);
  countN_k<<<NB, 256, 0, stream>>>(pairs, base, cnt, dd, N);
  scan1_k<<<nbN, 256, 0, stream>>>(cnt, rs, bsum, N);
  scan2_k<<<1, 512, 0, stream>>>(bsum, boff, nbN);
  scan3_k<<<nbN, 256, 0, stream>>>(rs, boff, N);
  partC_k<<<NB, 256, 0, stream>>>(pairs, base, rs, csr, N);

  const int mtiles = (N + 127) / 128;
  const int sgroups = (mtiles + 7) / 8;
  gemm1_k<<<sgroups * 32, 256, 0, stream>>>(x, W1t, bm0, bv0, Hcat, N, 512, mtiles);
  gemm2_k<<<mtiles, 256, 0, stream>>>(Hcat, W2t, bm1, bv1, Mcat, N, 512);
  spmm_final_k<<<(N + 3) / 4, 256, 0, stream>>>(Mcat, dd, rs, cnt, csr, sample, out, N);
}